// Round 1
// baseline (748.182 us; speedup 1.0000x reference)
//
#include <hip/hip_runtime.h>

// Problem constants (match reference)
#define Gn 256
#define Nn 512
#define En 4096
#define Fn 64
#define Cn 16
#define XS 66   // padded LDS stride for aggregated features: 66 -> row n starts at
                // bank (n*66)%32 = (2n)%32, conflict-free for the 8 node-groups a
                // wave touches per GEMM step; even so scalar-zeroing is simple.

// One block per graph. 1024 threads = 16 waves. Full fusion:
//   deg -> dinv -> xh = \hat{A} x (scatter into LDS) -> h = relu(xh W^T + b) in regs
//   -> per-thread logits partials vs lin_weight -> wave+block reduce -> log_softmax.
// Uses associativity: \hat{A}(XW) == (\hat{A}X)W, so only ONE 512x64 array is live.
__global__ __launch_bounds__(1024) void gcn_fused(
    const float* __restrict__ x,      // [G,N,F]
    const int*   __restrict__ ei,     // [G,2,E]
    const float* __restrict__ w,      // [F_OUT,F_IN] = [64,64]
    const float* __restrict__ wbias,  // [64]
    const float* __restrict__ lw,     // [C, N*F]
    const float* __restrict__ lbias,  // [C]
    float* __restrict__ out)          // [G,C]
{
    __shared__ float xh[Nn * XS];     // 132 KB aggregated features
    __shared__ float dinv[Nn];        // 2 KB: degree, then rsqrt(degree)
    __shared__ float wt[Fn * Fn];     // 16 KB: wt[f*64+o] = w[o*64+f]
    __shared__ float wred[16][Cn];    // 1 KB: per-wave logit partials

    const int g    = blockIdx.x;
    const int tid  = threadIdx.x;
    const int lane = tid & 63;
    const int wid  = tid >> 6;        // 0..15

    const float* xg = x + (size_t)g * Nn * Fn;
    const int*   es = ei + (size_t)g * 2 * En;   // sources (row)
    const int*   ed = es + En;                    // targets (col)

    // ---- init: zero xh, deg=1 (self-loop), transpose W into LDS ----
    for (int i = tid; i < Nn * XS; i += 1024) xh[i] = 0.0f;
    if (tid < Nn) dinv[tid] = 1.0f;
    for (int i = tid; i < Fn * Fn; i += 1024) {
        int o = i >> 6, f = i & 63;
        wt[f * Fn + o] = w[i];        // coalesced read; one-time write conflicts ok
    }
    __syncthreads();

    // ---- degree at targets ----
    for (int e = tid; e < En; e += 1024) {
        atomicAdd(&dinv[ed[e]], 1.0f);
    }
    __syncthreads();
    if (tid < Nn) dinv[tid] = rsqrtf(dinv[tid]);  // deg >= 1 always (self-loop)
    __syncthreads();

    // ---- aggregate: xh[t] += dinv[s]*dinv[t] * x[s]  (one wave per edge) ----
    for (int e = wid; e < En + Nn; e += 16) {
        int s, t; float nrm;
        if (e < En) {
            s = es[e]; t = ed[e];
            nrm = dinv[s] * dinv[t];
        } else {                       // self-loops
            s = e - En; t = s;
            float d = dinv[s];
            nrm = d * d;
        }
        float v = xg[s * Fn + lane];               // 256B coalesced, L2-hot
        atomicAdd(&xh[t * XS + lane], nrm * v);    // ds f32 atomic, 2-way banks
    }
    __syncthreads();

    // ---- conv GEMM: h = relu(xh @ W^T + b); thread tile = 4 nodes x 8 outs ----
    const int o8 = (tid & 7) * 8;     // output base (8 consecutive outputs)
    const int ng = tid >> 3;          // node group 0..127; nodes ng + i*128
    float acc[4][8];
    #pragma unroll
    for (int i = 0; i < 4; ++i)
        #pragma unroll
        for (int j = 0; j < 8; ++j) acc[i][j] = 0.0f;

    for (int f = 0; f < Fn; ++f) {
        float4 wa = *(const float4*)&wt[f * Fn + o8];
        float4 wb4 = *(const float4*)&wt[f * Fn + o8 + 4];
        float wv[8] = {wa.x, wa.y, wa.z, wa.w, wb4.x, wb4.y, wb4.z, wb4.w};
        #pragma unroll
        for (int i = 0; i < 4; ++i) {
            float xv = xh[(ng + i * 128) * XS + f];
            #pragma unroll
            for (int j = 0; j < 8; ++j) acc[i][j] += xv * wv[j];
        }
    }

    {
        float4 ba = *(const float4*)&wbias[o8];
        float4 bb = *(const float4*)&wbias[o8 + 4];
        float bv[8] = {ba.x, ba.y, ba.z, ba.w, bb.x, bb.y, bb.z, bb.w};
        #pragma unroll
        for (int i = 0; i < 4; ++i)
            #pragma unroll
            for (int j = 0; j < 8; ++j)
                acc[i][j] = fmaxf(acc[i][j] + bv[j], 0.0f);
    }

    // ---- final linear partials: p[c] += sum h[n][o] * lw[c][n*64+o] ----
    float p[Cn];
    #pragma unroll
    for (int c = 0; c < Cn; ++c) p[c] = 0.0f;

    for (int c = 0; c < Cn; ++c) {
        const float* lwc = lw + (size_t)c * (Nn * Fn);
        #pragma unroll
        for (int i = 0; i < 4; ++i) {
            const float* src = &lwc[(ng + i * 128) * Fn + o8];
            float4 a = *(const float4*)src;        // coalesced: wave reads 2KB run
            float4 b = *(const float4*)(src + 4);
            p[c] += acc[i][0]*a.x + acc[i][1]*a.y + acc[i][2]*a.z + acc[i][3]*a.w
                  + acc[i][4]*b.x + acc[i][5]*b.y + acc[i][6]*b.z + acc[i][7]*b.w;
        }
    }

    // ---- reduce partials: wave shuffle -> LDS -> wave 0 ----
    #pragma unroll
    for (int c = 0; c < Cn; ++c) {
        float v = p[c];
        #pragma unroll
        for (int off = 32; off > 0; off >>= 1) v += __shfl_down(v, off, 64);
        if (lane == 0) wred[wid][c] = v;
    }
    __syncthreads();

    if (wid == 0 && lane < Cn) {
        float v = lbias[lane];
        #pragma unroll
        for (int k = 0; k < 16; ++k) v += wred[k][lane];
        // log_softmax across the 16 lanes holding the 16 classes
        float m = v;
        #pragma unroll
        for (int off = 8; off > 0; off >>= 1) m = fmaxf(m, __shfl_xor(m, off, 16));
        float ex = expf(v - m);
        float s = ex;
        #pragma unroll
        for (int off = 8; off > 0; off >>= 1) s += __shfl_xor(s, off, 16);
        out[g * Cn + lane] = v - m - logf(s);
    }
}

extern "C" void kernel_launch(void* const* d_in, const int* in_sizes, int n_in,
                              void* d_out, int out_size, void* d_ws, size_t ws_size,
                              hipStream_t stream) {
    const float* x  = (const float*)d_in[0];
    const int*   ei = (const int*)d_in[1];
    const float* w  = (const float*)d_in[2];
    const float* wb = (const float*)d_in[3];
    const float* lw = (const float*)d_in[4];
    const float* lb = (const float*)d_in[5];
    float* out = (float*)d_out;
    hipLaunchKernelGGL(gcn_fused, dim3(Gn), dim3(1024), 0, stream,
                       x, ei, w, wb, lw, lb, out);
}

// Round 2
// 692.590 us; speedup vs baseline: 1.0803x; 1.0803x over previous
//
#include <hip/hip_runtime.h>

// Problem constants (match reference)
#define Gn 256
#define Nn 512
#define En 4096
#define Fn 64
#define Cn 16
#define XS 66   // padded LDS stride: row n starts at bank (2n)%32 -> the 8 node-
                // groups a wave touches per GEMM step hit distinct banks.

// One block per graph (256 blocks = 256 CUs), 1024 threads = 16 waves.
// Full fusion using \hat{A}(XW) == (\hat{A}X)W:
//   deg -> dinv -> xh = \hat{A} x (LDS scatter) -> h = relu(xh W^T + b) in regs
//   -> logits partials vs lin_weight -> reduce -> log_softmax.
// __launch_bounds__(1024, 4): LDS (151KB) forces 1 block/CU = 4 waves/EU, so
// allow the full 128 VGPRs that occupancy permits. At the default heuristic the
// compiler picked 64 VGPRs and spilled acc[4][8]+p[16] to scratch (403 MB of
// HBM write traffic, R1 counters).
__global__ __launch_bounds__(1024, 4) void gcn_fused(
    const float* __restrict__ x,      // [G,N,F]
    const int*   __restrict__ ei,     // [G,2,E]
    const float* __restrict__ w,      // [F_OUT,F_IN] = [64,64]
    const float* __restrict__ wbias,  // [64]
    const float* __restrict__ lw,     // [C, N*F]
    const float* __restrict__ lbias,  // [C]
    float* __restrict__ out)          // [G,C]
{
    __shared__ float xh[Nn * XS];     // 132 KB aggregated features
    __shared__ float dinv[Nn];        // 2 KB: degree, then rsqrt(degree)
    __shared__ float wt[Fn * Fn];     // 16 KB: wt[f*64+o] = w[o*64+f]
    __shared__ float wred[16][Cn];    // 1 KB: per-wave logit partials

    const int g    = blockIdx.x;
    const int tid  = threadIdx.x;
    const int lane = tid & 63;
    const int wid  = tid >> 6;        // 0..15

    const float* xg = x + (size_t)g * Nn * Fn;
    const int*   es = ei + (size_t)g * 2 * En;   // sources (row)
    const int*   ed = es + En;                    // targets (col)

    // ---- init: deg=1 (self-loop), transpose W into LDS ----
    if (tid < Nn) dinv[tid] = 1.0f;
    for (int i = tid; i < Fn * Fn; i += 1024) {
        int o = i >> 6, f = i & 63;
        wt[f * Fn + o] = w[i];        // coalesced read; one-time write conflicts ok
    }
    __syncthreads();

    // ---- degree at targets ----
    for (int e = tid; e < En; e += 1024) {
        atomicAdd(&dinv[ed[e]], 1.0f);
    }
    __syncthreads();
    if (tid < Nn) dinv[tid] = rsqrtf(dinv[tid]);  // deg >= 1 always (self-loop)
    __syncthreads();

    // ---- init xh with the self-loop term (non-atomic; replaces zero-fill) ----
    {
        const int n0 = wid * 32;
        for (int n = n0; n < n0 + 32; ++n) {
            float d = dinv[n];
            xh[n * XS + lane] = d * d * xg[n * Fn + lane];
        }
    }
    __syncthreads();

    // ---- aggregate edges: xh[t] += dinv[s]*dinv[t]*x[s]; wave per edge, x4 MLP ----
    {
        const int ebase = wid * (En / 16);        // 256 edges per wave
        for (int k = 0; k < En / 16; k += 4) {
            int e = ebase + k;
            int s0 = es[e], s1 = es[e+1], s2 = es[e+2], s3 = es[e+3];
            int t0 = ed[e], t1 = ed[e+1], t2 = ed[e+2], t3 = ed[e+3];
            float n0 = dinv[s0] * dinv[t0];
            float n1 = dinv[s1] * dinv[t1];
            float n2 = dinv[s2] * dinv[t2];
            float n3 = dinv[s3] * dinv[t3];
            float v0 = xg[s0 * Fn + lane];        // 4 independent 256B loads in flight
            float v1 = xg[s1 * Fn + lane];
            float v2 = xg[s2 * Fn + lane];
            float v3 = xg[s3 * Fn + lane];
            atomicAdd(&xh[t0 * XS + lane], n0 * v0);
            atomicAdd(&xh[t1 * XS + lane], n1 * v1);
            atomicAdd(&xh[t2 * XS + lane], n2 * v2);
            atomicAdd(&xh[t3 * XS + lane], n3 * v3);
        }
    }
    __syncthreads();

    // ---- conv GEMM: h = relu(xh @ W^T + b); thread tile = 4 nodes x 8 outs ----
    const int o8 = (tid & 7) * 8;     // output base (8 consecutive outputs)
    const int ng = tid >> 3;          // node group 0..127; nodes ng + i*128
    float acc[4][8];
    #pragma unroll
    for (int i = 0; i < 4; ++i)
        #pragma unroll
        for (int j = 0; j < 8; ++j) acc[i][j] = 0.0f;

    #pragma unroll 4
    for (int f = 0; f < Fn; ++f) {
        float4 wa  = *(const float4*)&wt[f * Fn + o8];
        float4 wb4 = *(const float4*)&wt[f * Fn + o8 + 4];
        float wv[8] = {wa.x, wa.y, wa.z, wa.w, wb4.x, wb4.y, wb4.z, wb4.w};
        #pragma unroll
        for (int i = 0; i < 4; ++i) {
            float xv = xh[(ng + i * 128) * XS + f];
            #pragma unroll
            for (int j = 0; j < 8; ++j) acc[i][j] += xv * wv[j];
        }
    }

    {
        float4 ba = *(const float4*)&wbias[o8];
        float4 bb = *(const float4*)&wbias[o8 + 4];
        float bv[8] = {ba.x, ba.y, ba.z, ba.w, bb.x, bb.y, bb.z, bb.w};
        #pragma unroll
        for (int i = 0; i < 4; ++i)
            #pragma unroll
            for (int j = 0; j < 8; ++j)
                acc[i][j] = fmaxf(acc[i][j] + bv[j], 0.0f);
    }

    // ---- final linear partials: p[c] += sum h[n][o] * lw[c][n*64+o] ----
    float p[Cn];
    #pragma unroll
    for (int c = 0; c < Cn; ++c) p[c] = 0.0f;

    #pragma unroll
    for (int c = 0; c < Cn; ++c) {
        const float* lwc = lw + (size_t)c * (Nn * Fn);
        #pragma unroll
        for (int i = 0; i < 4; ++i) {
            const float* src = &lwc[(ng + i * 128) * Fn + o8];
            float4 a = *(const float4*)src;        // coalesced: wave reads 2KB run
            float4 b = *(const float4*)(src + 4);
            p[c] += acc[i][0]*a.x + acc[i][1]*a.y + acc[i][2]*a.z + acc[i][3]*a.w
                  + acc[i][4]*b.x + acc[i][5]*b.y + acc[i][6]*b.z + acc[i][7]*b.w;
        }
    }

    // ---- reduce partials: wave shuffle -> LDS -> wave 0 ----
    #pragma unroll
    for (int c = 0; c < Cn; ++c) {
        float v = p[c];
        #pragma unroll
        for (int off = 32; off > 0; off >>= 1) v += __shfl_down(v, off, 64);
        if (lane == 0) wred[wid][c] = v;
    }
    __syncthreads();

    if (wid == 0 && lane < Cn) {
        float v = lbias[lane];
        #pragma unroll
        for (int k = 0; k < 16; ++k) v += wred[k][lane];
        // log_softmax across the 16 lanes holding the 16 classes
        float m = v;
        #pragma unroll
        for (int off = 8; off > 0; off >>= 1) m = fmaxf(m, __shfl_xor(m, off, 16));
        float ex = expf(v - m);
        float s = ex;
        #pragma unroll
        for (int off = 8; off > 0; off >>= 1) s += __shfl_xor(s, off, 16);
        out[g * Cn + lane] = v - m - logf(s);
    }
}

extern "C" void kernel_launch(void* const* d_in, const int* in_sizes, int n_in,
                              void* d_out, int out_size, void* d_ws, size_t ws_size,
                              hipStream_t stream) {
    const float* x  = (const float*)d_in[0];
    const int*   ei = (const int*)d_in[1];
    const float* w  = (const float*)d_in[2];
    const float* wb = (const float*)d_in[3];
    const float* lw = (const float*)d_in[4];
    const float* lb = (const float*)d_in[5];
    float* out = (float*)d_out;
    hipLaunchKernelGGL(gcn_fused, dim3(Gn), dim3(1024), 0, stream,
                       x, ei, w, wb, lw, lb, out);
}

// Round 3
// 459.904 us; speedup vs baseline: 1.6268x; 1.5059x over previous
//
#include <hip/hip_runtime.h>

// Problem constants (match reference)
#define Gn 256
#define Nn 512
#define En 4096
#define Fn 64
#define Cn 16
#define XS 68   // xh row stride in floats. Multiple of 4 => n*XS is 16B-aligned
                // (float4-safe). 68%32=4 => 8 consecutive rows land on distinct
                // bank groups (step 4), so 8-row broadcast reads are conflict-free.

// One block per graph (256 blocks = 256 CUs), 1024 threads = 16 waves.
// Full fusion via \hat{A}(XW) == (\hat{A}X)W:
//   deg -> dinv -> xh = \hat{A}x (LDS scatter)
//   -> per 256-node chunk: h = relu(xh W^T + b) IN-PLACE over xh
//   -> linear: wave w <-> class w, scalar accumulator per lane
//   -> reduce -> log_softmax.
// Max live per-thread state: conv = acc0[8]+acc1[8]+8 wt+2 xh ~ 40 VGPR;
// linear = 2 scalars + 4 float4 ~ 20 VGPR. Spill-proof even at a 64-VGPR cap
// (R1/R2 lost 10x to scratch: p[16]+acc[4][8] live together -> 400MB WRITE_SIZE).
__global__ __launch_bounds__(1024, 4) void gcn_fused(
    const float* __restrict__ x,      // [G,N,F]
    const int*   __restrict__ ei,     // [G,2,E]
    const float* __restrict__ w,      // [F_OUT,F_IN] = [64,64]
    const float* __restrict__ wbias,  // [64]
    const float* __restrict__ lw,     // [C, N*F]
    const float* __restrict__ lbias,  // [C]
    float* __restrict__ out)          // [G,C]
{
    __shared__ float xh[Nn * XS];     // 136 KB: aggregated features, then h
    __shared__ float dinv[Nn];        // 2 KB
    __shared__ float wt[Fn * Fn];     // 16 KB: wt[f*64+o] = w[o*64+f]
    __shared__ float wred[16];        // per-wave (= per-class) logit partials

    const int g    = blockIdx.x;
    const int tid  = threadIdx.x;
    const int lane = tid & 63;
    const int wid  = tid >> 6;        // 0..15

    const float* xg = x + (size_t)g * Nn * Fn;
    const int*   es = ei + (size_t)g * 2 * En;   // sources (row)
    const int*   ed = es + En;                    // targets (col)

    // ---- init: deg=1 (self-loop), transpose W into LDS ----
    if (tid < Nn) dinv[tid] = 1.0f;
    for (int i = tid; i < Fn * Fn; i += 1024) {
        int o = i >> 6, f = i & 63;
        wt[f * Fn + o] = w[i];
    }
    __syncthreads();

    // ---- degree at targets ----
    for (int e = tid; e < En; e += 1024) atomicAdd(&dinv[ed[e]], 1.0f);
    __syncthreads();
    if (tid < Nn) dinv[tid] = rsqrtf(dinv[tid]);  // deg >= 1 (self-loop)
    __syncthreads();

    // ---- init xh with the self-loop term (non-atomic) ----
    {
        const int n0 = wid * 32;
        for (int n = n0; n < n0 + 32; ++n) {
            float d = dinv[n];
            xh[n * XS + lane] = d * d * xg[n * Fn + lane];
        }
    }
    __syncthreads();

    // ---- aggregate edges: xh[t] += dinv[s]*dinv[t]*x[s]; wave per edge, x4 ILP ----
    {
        const int ebase = wid * (En / 16);        // 256 edges per wave
        for (int k = 0; k < En / 16; k += 4) {
            int e = ebase + k;
            int4 s4 = *(const int4*)&es[e];
            int4 t4 = *(const int4*)&ed[e];
            float n0 = dinv[s4.x] * dinv[t4.x];
            float n1 = dinv[s4.y] * dinv[t4.y];
            float n2 = dinv[s4.z] * dinv[t4.z];
            float n3 = dinv[s4.w] * dinv[t4.w];
            float v0 = xg[s4.x * Fn + lane];      // 4 independent 256B loads in flight
            float v1 = xg[s4.y * Fn + lane];
            float v2 = xg[s4.z * Fn + lane];
            float v3 = xg[s4.w * Fn + lane];
            atomicAdd(&xh[t4.x * XS + lane], n0 * v0);
            atomicAdd(&xh[t4.y * XS + lane], n1 * v1);
            atomicAdd(&xh[t4.z * XS + lane], n2 * v2);
            atomicAdd(&xh[t4.w * XS + lane], n3 * v3);
        }
    }
    __syncthreads();

    // ---- per-chunk conv (in-place) + linear ----
    const int s  = tid >> 3;          // node slot 0..127 within chunk
    const int o8 = (tid & 7) * 8;     // 8 consecutive conv outputs
    const int l4 = lane >> 4;         // linear-phase node sub-index
    const int lo = (lane & 15) * 4;   // linear-phase feature offset (floats)

    // conv bias for this thread's 8 outputs (registers, loaded once)
    float bv[8];
    {
        float4 ba = *(const float4*)&wbias[o8];
        float4 bb = *(const float4*)&wbias[o8 + 4];
        bv[0]=ba.x; bv[1]=ba.y; bv[2]=ba.z; bv[3]=ba.w;
        bv[4]=bb.x; bv[5]=bb.y; bv[6]=bb.z; bv[7]=bb.w;
    }

    float p0 = 0.0f, p1 = 0.0f;       // this lane's partial for class `wid`

    for (int k = 0; k < 2; ++k) {
        const int n0 = k * 256 + s;   // this thread's 2 nodes
        const int n1 = n0 + 128;

        // conv: h[n][o8..o8+7] = relu(sum_f xh[n][f]*wt[f][o], + bias)
        float acc0[8], acc1[8];
        #pragma unroll
        for (int j = 0; j < 8; ++j) { acc0[j] = 0.0f; acc1[j] = 0.0f; }

        #pragma unroll 2
        for (int f = 0; f < Fn; ++f) {
            float4 wa  = *(const float4*)&wt[f * Fn + o8];
            float4 wb4 = *(const float4*)&wt[f * Fn + o8 + 4];
            float xv0 = xh[n0 * XS + f];          // 8-lane broadcast, banks ok
            float xv1 = xh[n1 * XS + f];
            acc0[0] += xv0 * wa.x;  acc1[0] += xv1 * wa.x;
            acc0[1] += xv0 * wa.y;  acc1[1] += xv1 * wa.y;
            acc0[2] += xv0 * wa.z;  acc1[2] += xv1 * wa.z;
            acc0[3] += xv0 * wa.w;  acc1[3] += xv1 * wa.w;
            acc0[4] += xv0 * wb4.x; acc1[4] += xv1 * wb4.x;
            acc0[5] += xv0 * wb4.y; acc1[5] += xv1 * wb4.y;
            acc0[6] += xv0 * wb4.z; acc1[6] += xv1 * wb4.z;
            acc0[7] += xv0 * wb4.w; acc1[7] += xv1 * wb4.w;
        }
        #pragma unroll
        for (int j = 0; j < 8; ++j) {
            acc0[j] = fmaxf(acc0[j] + bv[j], 0.0f);
            acc1[j] = fmaxf(acc1[j] + bv[j], 0.0f);
        }

        __syncthreads();              // all reads of this chunk's rows done
        // write h over xh (aligned: n*68 and o8 are multiples of 4 floats)
        *(float4*)&xh[n0 * XS + o8]     = make_float4(acc0[0], acc0[1], acc0[2], acc0[3]);
        *(float4*)&xh[n0 * XS + o8 + 4] = make_float4(acc0[4], acc0[5], acc0[6], acc0[7]);
        *(float4*)&xh[n1 * XS + o8]     = make_float4(acc1[0], acc1[1], acc1[2], acc1[3]);
        *(float4*)&xh[n1 * XS + o8 + 4] = make_float4(acc1[4], acc1[5], acc1[6], acc1[7]);
        __syncthreads();              // h visible

        // linear: wave `wid` accumulates class `wid` over this chunk's 16384 floats.
        // lane reads float4s: flat4 = i*64+lane; n_local = i*4+l4; off = lo.
        const float* lwc = lw + (size_t)wid * (Nn * Fn) + k * 16384;
        #pragma unroll 4
        for (int i = 0; i < 64; i += 2) {
            const float4 la = *(const float4*)(lwc + (size_t)(i * 64 + lane) * 4);
            const float4 lb = *(const float4*)(lwc + (size_t)((i + 1) * 64 + lane) * 4);
            const float4 ha = *(const float4*)&xh[(k * 256 + i * 4 + l4) * XS + lo];
            const float4 hb = *(const float4*)&xh[(k * 256 + (i + 1) * 4 + l4) * XS + lo];
            p0 += la.x * ha.x + la.y * ha.y + la.z * ha.z + la.w * ha.w;
            p1 += lb.x * hb.x + lb.y * hb.y + lb.z * hb.z + lb.w * hb.w;
        }
        // no trailing sync needed: next chunk's conv reads disjoint rows, and
        // its pre-write sync orders everything before the next overwrite.
    }

    // ---- reduce this wave's partial -> wred[wid] ----
    {
        float v = p0 + p1;
        #pragma unroll
        for (int off = 32; off > 0; off >>= 1) v += __shfl_down(v, off, 64);
        if (lane == 0) wred[wid] = v;
    }
    __syncthreads();

    // ---- log_softmax over 16 classes (wave 0, lanes 0..15) ----
    if (wid == 0 && lane < Cn) {
        float v = wred[lane] + lbias[lane];
        float m = v;
        #pragma unroll
        for (int off = 8; off > 0; off >>= 1) m = fmaxf(m, __shfl_xor(m, off, 16));
        float ex = expf(v - m);
        float ssum = ex;
        #pragma unroll
        for (int off = 8; off > 0; off >>= 1) ssum += __shfl_xor(ssum, off, 16);
        out[g * Cn + lane] = v - m - logf(ssum);
    }
}

extern "C" void kernel_launch(void* const* d_in, const int* in_sizes, int n_in,
                              void* d_out, int out_size, void* d_ws, size_t ws_size,
                              hipStream_t stream) {
    const float* x  = (const float*)d_in[0];
    const int*   ei = (const int*)d_in[1];
    const float* w  = (const float*)d_in[2];
    const float* wb = (const float*)d_in[3];
    const float* lw = (const float*)d_in[4];
    const float* lb = (const float*)d_in[5];
    float* out = (float*)d_out;
    hipLaunchKernelGGL(gcn_fused, dim3(Gn), dim3(1024), 0, stream,
                       x, ei, w, wb, lw, lb, out);
}

// Round 4
// 176.100 us; speedup vs baseline: 4.2486x; 2.6116x over previous
//
#include <hip/hip_runtime.h>

// Problem constants (match reference)
#define Gn 256
#define Nn 512
#define En 4096
#define Fn 64
#define Cn 16
#define XS 68   // xh row stride (floats): mult of 4 (float4-aligned); (68n)%32=4n
                // => 8 consecutive rows hit distinct bank groups.
#define KSL 16  // K-slices in the linear GEMM (32 nodes each)
#define GT 16   // graphs per linear tile

// ---------------- K1: aggregate (CSR gather, atomic-free) + conv ----------------
// One block per graph, 1024 thr = 16 waves, ~156 KB LDS -> 1 block/CU.
// deg -> dinv -> CSR(counts/scan/fill) -> per-target register gather (NO xh
// atomics; R3's 4608 scatter-atomics are the prime stall suspect) -> conv
// (bf16 wt, fp32 acc) -> h to global ws.
__global__ __launch_bounds__(1024, 4) void gcn_agg_conv(
    const float* __restrict__ x,      // [G,N,F]
    const int*   __restrict__ ei,     // [G,2,E]
    const float* __restrict__ w,      // [F_OUT,F_IN]
    const float* __restrict__ wbias,  // [64]
    float* __restrict__ hout)         // ws: [G,N,64] fp32
{
    __shared__ float xh[Nn * XS];             // 139,264 B
    __shared__ float dinv[Nn];                // 2 KB: degree -> rsqrt(degree)
    __shared__ int   cnt[Nn];                 // 2 KB: excl prefix -> incl prefix
    __shared__ unsigned short srcs[En];       // 8 KB: CSR source-node ids
    __shared__ unsigned short wts[Fn * Fn];   // 8 KB: wts[f*64+o] = bf16(w[o][f])
    __shared__ int wsum[8];

    const int g    = blockIdx.x;
    const int tid  = threadIdx.x;
    const int lane = tid & 63;
    const int wid  = tid >> 6;

    const float* xg = x + (size_t)g * Nn * Fn;
    const int*   es = ei + (size_t)g * 2 * En;   // sources
    const int*   ed = es + En;                    // targets

    // init deg (self-loop = 1) + stage transposed bf16 W
    if (tid < Nn) dinv[tid] = 1.0f;
    for (int i = tid; i < Fn * Fn; i += 1024) {
        unsigned u = __float_as_uint(w[i]);       // i = o*64+f, coalesced
        unsigned short b = (unsigned short)((u + 0x7fffu + ((u >> 16) & 1u)) >> 16);
        wts[(i & 63) * Fn + (i >> 6)] = b;        // RNE bf16, transposed scatter
    }
    __syncthreads();

    // degree at targets (4096 small LDS atomics — cheap)
    for (int e = tid; e < En; e += 1024) atomicAdd(&dinv[ed[e]], 1.0f);
    __syncthreads();

    // per-node edge count + dinv
    int c = 0;
    if (tid < Nn) {
        float d = dinv[tid];
        c = (int)d - 1;                           // real in-edges (exact small int)
        dinv[tid] = rsqrtf(d);
    }
    // exclusive prefix scan of c over 512 nodes (waves 0..7; others c=0)
    int v = c;
    #pragma unroll
    for (int off = 1; off < 64; off <<= 1) {
        int u = __shfl_up(v, off, 64);
        if (lane >= off) v += u;
    }
    if (wid < 8 && lane == 63) wsum[wid] = v;
    __syncthreads();
    if (tid == 0) { int a = 0; for (int i = 0; i < 8; ++i) { int t = wsum[i]; wsum[i] = a; a += t; } }
    __syncthreads();
    if (tid < Nn) cnt[tid] = v - c + wsum[wid];   // exclusive prefix
    __syncthreads();

    // CSR fill: slot = fetch-and-inc; afterwards cnt[t] = inclusive prefix,
    // so row t spans [cnt[t-1], cnt[t]).
    for (int e = tid; e < En; e += 1024) {
        int t = ed[e];
        int slot = atomicAdd(&cnt[t], 1);
        srcs[slot] = (unsigned short)es[e];
    }
    __syncthreads();

    // aggregate: wave per target, REGISTER accumulate (lane = feature), one
    // plain LDS write per row. Gathers batched x4 for MLP.
    for (int i = 0; i < 32; ++i) {
        int t = wid + i * 16;                     // interleaved for balance
        int beg = (t == 0) ? 0 : cnt[t - 1];
        int end = cnt[t];
        float dt  = dinv[t];
        float acc = dt * dt * xg[t * Fn + lane];  // self-loop term
        int j = beg;
        for (; j + 4 <= end; j += 4) {
            int s0 = srcs[j], s1 = srcs[j+1], s2 = srcs[j+2], s3 = srcs[j+3];
            float n0 = dinv[s0] * dt, n1 = dinv[s1] * dt;
            float n2 = dinv[s2] * dt, n3 = dinv[s3] * dt;
            float v0 = xg[s0 * Fn + lane];        // 4 indep 256B loads in flight
            float v1 = xg[s1 * Fn + lane];
            float v2 = xg[s2 * Fn + lane];
            float v3 = xg[s3 * Fn + lane];
            acc += n0 * v0 + n1 * v1 + n2 * v2 + n3 * v3;
        }
        for (; j < end; ++j) {
            int s = srcs[j];
            acc += dinv[s] * dt * xg[s * Fn + lane];
        }
        xh[t * XS + lane] = acc;
    }
    __syncthreads();

    // conv: thread = 4 nodes x 8 outs; xh read as float4 (j = float4 idx),
    // wt as bf16x8 (uint4) unpacked by <<16. h -> global.
    const int o8 = (tid & 7) * 8;
    const int ng = tid >> 3;                      // 0..127
    float acc[4][8];
    #pragma unroll
    for (int i = 0; i < 4; ++i)
        #pragma unroll
        for (int k = 0; k < 8; ++k) acc[i][k] = 0.0f;

    #pragma unroll 4
    for (int j = 0; j < 16; ++j) {
        float4 q0 = *(const float4*)&xh[(ng +   0) * XS + j * 4];
        float4 q1 = *(const float4*)&xh[(ng + 128) * XS + j * 4];
        float4 q2 = *(const float4*)&xh[(ng + 256) * XS + j * 4];
        float4 q3 = *(const float4*)&xh[(ng + 384) * XS + j * 4];
        float xa[4][4] = {{q0.x,q0.y,q0.z,q0.w},{q1.x,q1.y,q1.z,q1.w},
                          {q2.x,q2.y,q2.z,q2.w},{q3.x,q3.y,q3.z,q3.w}};
        #pragma unroll
        for (int ff = 0; ff < 4; ++ff) {
            uint4 wu = *(const uint4*)&wts[(j * 4 + ff) * Fn + o8];
            float wv[8];
            wv[0] = __uint_as_float((wu.x & 0xffffu) << 16);
            wv[1] = __uint_as_float(wu.x & 0xffff0000u);
            wv[2] = __uint_as_float((wu.y & 0xffffu) << 16);
            wv[3] = __uint_as_float(wu.y & 0xffff0000u);
            wv[4] = __uint_as_float((wu.z & 0xffffu) << 16);
            wv[5] = __uint_as_float(wu.z & 0xffff0000u);
            wv[6] = __uint_as_float((wu.w & 0xffffu) << 16);
            wv[7] = __uint_as_float(wu.w & 0xffff0000u);
            #pragma unroll
            for (int i = 0; i < 4; ++i)
                #pragma unroll
                for (int k = 0; k < 8; ++k)
                    acc[i][k] += xa[i][ff] * wv[k];
        }
    }

    float4 b0 = *(const float4*)&wbias[o8];
    float4 b1 = *(const float4*)&wbias[o8 + 4];
    float bv[8] = {b0.x, b0.y, b0.z, b0.w, b1.x, b1.y, b1.z, b1.w};
    #pragma unroll
    for (int i = 0; i < 4; ++i) {
        int n = ng + i * 128;
        float* hp = hout + ((size_t)g * Nn + n) * Fn + o8;
        float4 r0 = make_float4(fmaxf(acc[i][0] + bv[0], 0.f), fmaxf(acc[i][1] + bv[1], 0.f),
                                fmaxf(acc[i][2] + bv[2], 0.f), fmaxf(acc[i][3] + bv[3], 0.f));
        float4 r1 = make_float4(fmaxf(acc[i][4] + bv[4], 0.f), fmaxf(acc[i][5] + bv[5], 0.f),
                                fmaxf(acc[i][6] + bv[6], 0.f), fmaxf(acc[i][7] + bv[7], 0.f));
        *(float4*)hp       = r0;
        *(float4*)(hp + 4) = r1;
    }
}

// ---------------- K2: tiled linear  part[sx][g][c] = <h[g], lw[c]> ----------------
// Block = 16 graphs x 16 classes, K-slice = 2048 (32 nodes). lw slice is shared
// by 16 graph-tiles -> L2-resident; h streamed once from HBM.
__global__ __launch_bounds__(256) void gcn_linear(
    const float* __restrict__ h,      // ws: [G,N*F]
    const float* __restrict__ lw,     // [C, N*F]
    float* __restrict__ part)         // ws: [KSL][G][C]
{
    __shared__ float hs[GT * 260];    // 16 rows x 256 + 4 pad
    __shared__ float ls[Cn * 260];
    const int sx  = blockIdx.x;       // K-slice
    const int gy  = blockIdx.y;       // graph tile
    const int tid = threadIdx.x;
    const int ci  = tid & 15;
    const int gi  = tid >> 4;

    float p = 0.0f;
    for (int c8 = 0; c8 < 8; ++c8) {  // 8 chunks x 256 floats = 2048 K
        __syncthreads();
        #pragma unroll
        for (int r = 0; r < 4; ++r) {
            int q = tid + r * 256;
            int row = q >> 6, j = q & 63;                 // row 0..15, float4 j 0..63
            size_t ko = (size_t)sx * 2048 + c8 * 256 + j * 4;
            float4 hv = *(const float4*)&h[(size_t)(gy * GT + row) * (Nn * Fn) + ko];
            *(float4*)&hs[row * 260 + j * 4] = hv;
            float4 lv = *(const float4*)&lw[(size_t)row * (Nn * Fn) + ko];
            *(float4*)&ls[row * 260 + j * 4] = lv;
        }
        __syncthreads();
        #pragma unroll 8
        for (int j = 0; j < 64; ++j) {
            float4 a = *(const float4*)&hs[gi * 260 + j * 4];
            float4 b = *(const float4*)&ls[ci * 260 + j * 4];
            p += a.x * b.x + a.y * b.y + a.z * b.z + a.w * b.w;
        }
    }
    part[(size_t)sx * (Gn * Cn) + (gy * GT + gi) * Cn + ci] = p;
}

// ---------------- K3: reduce slices + bias + log_softmax ----------------
__global__ __launch_bounds__(64) void gcn_softmax(
    const float* __restrict__ part, const float* __restrict__ lbias,
    float* __restrict__ out)
{
    const int g = blockIdx.x, lane = threadIdx.x;
    if (lane < Cn) {
        float v = lbias[lane];
        #pragma unroll
        for (int s = 0; s < KSL; ++s) v += part[(size_t)s * (Gn * Cn) + g * Cn + lane];
        float m = v;
        #pragma unroll
        for (int off = 8; off > 0; off >>= 1) m = fmaxf(m, __shfl_xor(m, off, 16));
        float ex = expf(v - m);
        float ssum = ex;
        #pragma unroll
        for (int off = 8; off > 0; off >>= 1) ssum += __shfl_xor(ssum, off, 16);
        out[g * Cn + lane] = v - m - logf(ssum);
    }
}

extern "C" void kernel_launch(void* const* d_in, const int* in_sizes, int n_in,
                              void* d_out, int out_size, void* d_ws, size_t ws_size,
                              hipStream_t stream) {
    const float* x  = (const float*)d_in[0];
    const int*   ei = (const int*)d_in[1];
    const float* w  = (const float*)d_in[2];
    const float* wb = (const float*)d_in[3];
    const float* lw = (const float*)d_in[4];
    const float* lb = (const float*)d_in[5];
    float* out  = (float*)d_out;

    float* hbuf = (float*)d_ws;                        // 8,388,608 floats = 32 MB
    float* part = hbuf + (size_t)Gn * Nn * Fn;         // + 65,536 floats = 256 KB

    hipLaunchKernelGGL(gcn_agg_conv, dim3(Gn), dim3(1024), 0, stream,
                       x, ei, w, wb, hbuf);
    hipLaunchKernelGGL(gcn_linear, dim3(KSL, Gn / GT), dim3(256), 0, stream,
                       hbuf, lw, part);
    hipLaunchKernelGGL(gcn_softmax, dim3(Gn), dim3(64), 0, stream,
                       part, lb, out);
}

// Round 5
// 115.268 us; speedup vs baseline: 6.4908x; 1.5277x over previous
//
#include <hip/hip_runtime.h>

// Problem constants
#define Gn 256
#define Nn 512
#define En 4096
#define Fn 64
#define Cn 16
#define ET (En + Nn)   // CSR slots including self-loops

typedef _Float16 halfv8 __attribute__((ext_vector_type(8)));
typedef _Float16 halfv4 __attribute__((ext_vector_type(4)));
typedef float    f32x4  __attribute__((ext_vector_type(4)));

// ---------------- K1: CSR build + LDS-f16 gather + MFMA conv ----------------
// One block per graph (256 = #CUs), 1024 thr = 16 waves, 161.8 KB LDS.
// Pipeline: deg -> dinv -> CSR fill with PACKED (src|f16 norm) incl self-loops
// -> quarter-wave register gather from f16 x in LDS (no global/L2 in the loop,
//    no dinv chain: one ds_read_b32 per edge yields src+norm)
// -> conv via mfma_f32_16x16x32_f16 (A = xh swizzled, B = w rows swizzled)
// -> h (f16) to global via LDS-coalesced copyout.
__global__ __launch_bounds__(1024, 4) void gcn_agg_conv(
    const float* __restrict__ x,      // [G,N,F]
    const int*   __restrict__ ei,     // [G,2,E]
    const float* __restrict__ w,      // [F_OUT,F_IN] = [64,64]
    const float* __restrict__ wbias,  // [64]
    _Float16* __restrict__ hout)      // ws: [G, N*F] f16
{
    __shared__ unsigned short xs_h[Nn * Fn];  // 64 KB: f16 x; reused for f16 h
    __shared__ unsigned short xhs[Nn * Fn];   // 64 KB: f16 aggregated, swizzled
    __shared__ unsigned short wts[Fn * Fn];   // 8 KB: f16 w rows, swizzled
    __shared__ unsigned int   epk[ET + 4];    // 18.4 KB: (src<<16)|f16(norm)
    __shared__ float dinv[Nn];                // degree -> rsqrt(degree)
    __shared__ int   cnt[Nn];                 // excl -> incl prefix
    __shared__ int   wsum[8];

    const int g    = blockIdx.x;
    const int tid  = threadIdx.x;
    const int lane = tid & 63;
    const int wid  = tid >> 6;

    const float* xg = x + (size_t)g * Nn * Fn;
    const int*   es = ei + (size_t)g * 2 * En;   // sources
    const int*   ed = es + En;                    // targets

    if (tid < Nn) dinv[tid] = 1.0f;               // self-loop counts as 1
    __syncthreads();

    // ---- degree atomics + stage x (f16) + stage w (f16, swizzled) ----
    for (int e = tid; e < En; e += 1024) atomicAdd(&dinv[ed[e]], 1.0f);
    #pragma unroll
    for (int it = 0; it < 8; ++it) {
        int idx = tid + it * 1024;                // float4 index (8192 total)
        float4 v = *(const float4*)(xg + idx * 4);
        halfv4 hv; hv[0]=(_Float16)v.x; hv[1]=(_Float16)v.y;
                   hv[2]=(_Float16)v.z; hv[3]=(_Float16)v.w;
        *(halfv4*)((char*)xs_h + idx * 8) = hv;   // natural [n][f] layout
    }
    {
        int o = tid >> 4, f0 = (tid & 15) * 4;    // 4096 elems / 1024 thr
        float4 v = *(const float4*)(w + o * Fn + f0);
        halfv4 hv; hv[0]=(_Float16)v.x; hv[1]=(_Float16)v.y;
                   hv[2]=(_Float16)v.z; hv[3]=(_Float16)v.w;
        int blk = f0 >> 3, hf = (f0 >> 2) & 1;    // 16B-block XOR swizzle by row
        *(halfv4*)((char*)wts + o * 128 + ((blk ^ (o & 7)) * 16) + hf * 8) = hv;
    }
    __syncthreads();

    // ---- per-node slot count (incl self) + dinv; exclusive prefix scan ----
    int c = 0;
    if (tid < Nn) { float d = dinv[tid]; c = (int)d; dinv[tid] = rsqrtf(d); }
    int v_ = c;
    #pragma unroll
    for (int off = 1; off < 64; off <<= 1) {
        int u = __shfl_up(v_, off, 64);
        if (lane >= off) v_ += u;
    }
    if (wid < 8 && lane == 63) wsum[wid] = v_;
    __syncthreads();
    if (tid == 0) { int a = 0; for (int i = 0; i < 8; ++i) { int t = wsum[i]; wsum[i] = a; a += t; } }
    __syncthreads();
    if (tid < Nn) cnt[tid] = v_ - c + wsum[wid];
    __syncthreads();

    // ---- CSR fill (edges + self-loops) with packed src|norm ----
    for (int e = tid; e < ET; e += 1024) {
        int s, t;
        if (e < En) { s = es[e]; t = ed[e]; } else { s = e - En; t = s; }
        float nrm = dinv[s] * dinv[t];
        int slot = atomicAdd(&cnt[t], 1);         // cnt becomes inclusive prefix
        unsigned short nb = __builtin_bit_cast(unsigned short, (_Float16)nrm);
        epk[slot] = ((unsigned)s << 16) | nb;
    }
    __syncthreads();

    // ---- gather: quarter-wave per target, all-LDS, prefetched ----
    {
        const int qid = lane >> 4, fl = lane & 15;  // lane owns features fl*4..+3
        for (int r = 0; r < 8; ++r) {
            int t = r * 64 + wid * 4 + qid;
            int beg = (t == 0) ? 0 : cnt[t - 1];
            int end = cnt[t];
            float a0 = 0.f, a1 = 0.f, a2 = 0.f, a3 = 0.f;
            unsigned pk = epk[beg];
            for (int j = beg; j < end; ++j) {
                unsigned pkn = epk[j + 1];          // prefetch (padded array)
                int s = pk >> 16;
                float nrm = (float)__builtin_bit_cast(_Float16,
                                (unsigned short)(pk & 0xffffu));
                halfv4 xv = *(const halfv4*)((const char*)xs_h + s * 128 + fl * 8);
                a0 += nrm * (float)xv[0]; a1 += nrm * (float)xv[1];
                a2 += nrm * (float)xv[2]; a3 += nrm * (float)xv[3];
                pk = pkn;
            }
            halfv4 hv; hv[0]=(_Float16)a0; hv[1]=(_Float16)a1;
                       hv[2]=(_Float16)a2; hv[3]=(_Float16)a3;
            // swizzled write: 16B block (fl>>1) XOR (t&7), half (fl&1)
            int dw = t * 32 + (((fl >> 1) ^ (t & 7)) * 4) + (fl & 1) * 2;
            *(halfv4*)((char*)xhs + dw * 4) = hv;
        }
    }
    __syncthreads();

    // ---- conv: h = relu(xh @ W^T + b) via MFMA 16x16x32 f16 ----
    // A[m=lane&15][k=q*8+j] from xhs row n (swizzled blocks); B[k][n=lane&15]
    // = w[o][k] from wts row o (same swizzle). D: row=q*4+reg, col=lane&15.
    {
        const int m = lane & 15, q = lane >> 4;
        #pragma unroll
        for (int j = 0; j < 8; ++j) {
            int idx = wid * 8 + j, tm = idx >> 2, to = idx & 3;
            int n = tm * 16 + m, o = to * 16 + m;
            halfv8 A0 = *(const halfv8*)((const char*)xhs + n * 128 + ((q       ^ (n & 7)) * 16));
            halfv8 A1 = *(const halfv8*)((const char*)xhs + n * 128 + (((4 + q) ^ (n & 7)) * 16));
            halfv8 B0 = *(const halfv8*)((const char*)wts + o * 128 + ((q       ^ (o & 7)) * 16));
            halfv8 B1 = *(const halfv8*)((const char*)wts + o * 128 + (((4 + q) ^ (o & 7)) * 16));
            f32x4 acc = {0.f, 0.f, 0.f, 0.f};
            acc = __builtin_amdgcn_mfma_f32_16x16x32_f16(A0, B0, acc, 0, 0, 0);
            acc = __builtin_amdgcn_mfma_f32_16x16x32_f16(A1, B1, acc, 0, 0, 0);
            float bb = wbias[o];
            #pragma unroll
            for (int rreg = 0; rreg < 4; ++rreg) {
                int nn = tm * 16 + q * 4 + rreg;
                float hv = fmaxf(acc[rreg] + bb, 0.0f);
                xs_h[nn * 64 + o] = __builtin_bit_cast(unsigned short, (_Float16)hv);
            }
        }
    }
    __syncthreads();

    // ---- coalesced copyout: h (f16) -> global ----
    {
        _Float16* hg = hout + (size_t)g * (Nn * Fn);
        #pragma unroll
        for (int it = 0; it < 8; ++it) {
            int flat = tid + it * 1024;             // b64 index (8192 total)
            uint2 vv = *(const uint2*)((const char*)xs_h + flat * 8);
            *(uint2*)((char*)hg + flat * 8) = vv;
        }
    }
}

// ---------------- K2: logits partials via MFMA, frags from global ----------------
// GEMM [256 x 32768] (h, f16) x [32768 x 16] (lw^T, fp32->f16). Grid: 32
// k-chunks x 16 g-tiles; block = 4 waves = 4 k-quarters; in-block reduce.
__global__ __launch_bounds__(256) void gcn_linear(
    const _Float16* __restrict__ h,   // ws: [256][32768] f16
    const float* __restrict__ lw,     // [16][32768] fp32
    float* __restrict__ part)         // ws: [32][256][16] fp32
{
    __shared__ float red[4][64][4];
    const int cx = blockIdx.x;        // k-chunk (1024)
    const int gy = blockIdx.y;        // graph tile (16)
    const int tid = threadIdx.x, lane = tid & 63, wid = tid >> 6;
    const int ml = lane & 15, q = lane >> 4;

    const size_t kbase = (size_t)cx * 1024 + wid * 256;
    const _Float16* ha = h  + (size_t)(gy * 16 + ml) * (Nn * Fn) + kbase + q * 8;
    const float*    lb = lw + (size_t)ml * (Nn * Fn) + kbase + q * 8;

    f32x4 acc = {0.f, 0.f, 0.f, 0.f};
    #pragma unroll
    for (int ks = 0; ks < 8; ++ks) {
        halfv8 a = *(const halfv8*)(ha + ks * 32);
        float4 b0 = *(const float4*)(lb + ks * 32);
        float4 b1 = *(const float4*)(lb + ks * 32 + 4);
        halfv8 b; b[0]=(_Float16)b0.x; b[1]=(_Float16)b0.y; b[2]=(_Float16)b0.z;
                  b[3]=(_Float16)b0.w; b[4]=(_Float16)b1.x; b[5]=(_Float16)b1.y;
                  b[6]=(_Float16)b1.z; b[7]=(_Float16)b1.w;
        acc = __builtin_amdgcn_mfma_f32_16x16x32_f16(a, b, acc, 0, 0, 0);
    }
    #pragma unroll
    for (int r = 0; r < 4; ++r) red[wid][lane][r] = acc[r];
    __syncthreads();
    {
        int m = tid >> 4, cc = tid & 15;          // D: row=(lane>>4)*4+reg, col=lane&15
        int sl = (m >> 2) * 16 + cc, rg = m & 3;
        float v = red[0][sl][rg] + red[1][sl][rg] + red[2][sl][rg] + red[3][sl][rg];
        part[((size_t)cx * Gn + gy * 16 + m) * Cn + cc] = v;
    }
}

// ---------------- K3: reduce 32 slices + bias + log_softmax ----------------
__global__ __launch_bounds__(64) void gcn_softmax(
    const float* __restrict__ part, const float* __restrict__ lbias,
    float* __restrict__ out)
{
    const int g = blockIdx.x, lane = threadIdx.x;
    if (lane < Cn) {
        float v = lbias[lane];
        #pragma unroll
        for (int s = 0; s < 32; ++s) v += part[((size_t)s * Gn + g) * Cn + lane];
        float m = v;
        #pragma unroll
        for (int off = 8; off > 0; off >>= 1) m = fmaxf(m, __shfl_xor(m, off, 16));
        float ex = expf(v - m);
        float ssum = ex;
        #pragma unroll
        for (int off = 8; off > 0; off >>= 1) ssum += __shfl_xor(ssum, off, 16);
        out[g * Cn + lane] = v - m - logf(ssum);
    }
}

extern "C" void kernel_launch(void* const* d_in, const int* in_sizes, int n_in,
                              void* d_out, int out_size, void* d_ws, size_t ws_size,
                              hipStream_t stream) {
    const float* x  = (const float*)d_in[0];
    const int*   ei = (const int*)d_in[1];
    const float* w  = (const float*)d_in[2];
    const float* wb = (const float*)d_in[3];
    const float* lw = (const float*)d_in[4];
    const float* lb = (const float*)d_in[5];
    float* out = (float*)d_out;

    _Float16* hbuf = (_Float16*)d_ws;                       // 16 MB
    float* part = (float*)((char*)d_ws + (size_t)Gn * Nn * Fn * 2);  // 512 KB

    hipLaunchKernelGGL(gcn_agg_conv, dim3(Gn), dim3(1024), 0, stream,
                       x, ei, w, wb, hbuf);
    hipLaunchKernelGGL(gcn_linear, dim3(32, 16), dim3(256), 0, stream,
                       hbuf, lw, part);
    hipLaunchKernelGGL(gcn_softmax, dim3(Gn), dim3(64), 0, stream,
                       part, lb, out);
}

// Round 6
// 113.431 us; speedup vs baseline: 6.5959x; 1.0162x over previous
//
#include <hip/hip_runtime.h>

// Problem constants
#define Gn 256
#define Nn 512
#define En 4096
#define Fn 64
#define Cn 16
#define ET (En + Nn)   // CSR slots including self-loops

typedef _Float16 halfv8 __attribute__((ext_vector_type(8)));
typedef _Float16 halfv4 __attribute__((ext_vector_type(4)));
typedef float    f32x4  __attribute__((ext_vector_type(4)));

__device__ __forceinline__ float pk_norm(unsigned p) {
    return (float)__builtin_bit_cast(_Float16, (unsigned short)(p & 0xffffu));
}

// ---------------- K1: CSR build + LDS-f16 gather + MFMA conv ----------------
// One block per graph (256 = #CUs), 1024 thr = 16 waves, ~158 KB LDS.
// R6 changes vs R5: (1) gather pipelined 4 edges/iter with prefetched quad of
// packed (src|norm) words -> loop-carried LDS latency /4; (2) conv computes
// transposed tiles (A=W, B=xh) so each lane's 4 D-values are o-contiguous ->
// ONE swizzled ds_write_b64 per tile instead of 4 scalar ds_write_b16 with
// 8-way conflicts (R5's modeled ~10us epilogue).
__global__ __launch_bounds__(1024, 4) void gcn_agg_conv(
    const float* __restrict__ x,      // [G,N,F]
    const int*   __restrict__ ei,     // [G,2,E]
    const float* __restrict__ w,      // [F_OUT,F_IN] = [64,64]
    const float* __restrict__ wbias,  // [64]
    _Float16* __restrict__ hout)      // ws: [G, N*F] f16
{
    __shared__ unsigned short xs_h[Nn * Fn];  // 64 KB: f16 x; reused for f16 h
    __shared__ unsigned short xhs[Nn * Fn];   // 64 KB: f16 aggregated, swizzled
    __shared__ unsigned short wts[Fn * Fn];   // 8 KB: f16 w rows, swizzled
    __shared__ unsigned int   epk[ET + 8];    // 18.5 KB: (src<<16)|f16(norm)
    __shared__ float dinv[Nn];                // degree -> rsqrt(degree)
    __shared__ int   cnt[Nn];                 // excl -> incl prefix
    __shared__ int   wsum[8];

    const int g    = blockIdx.x;
    const int tid  = threadIdx.x;
    const int lane = tid & 63;
    const int wid  = tid >> 6;

    const float* xg = x + (size_t)g * Nn * Fn;
    const int*   es = ei + (size_t)g * 2 * En;   // sources
    const int*   ed = es + En;                    // targets

    if (tid < Nn) dinv[tid] = 1.0f;               // self-loop counts as 1
    __syncthreads();

    // ---- degree atomics + stage x (f16) + stage w (f16, swizzled) ----
    for (int e = tid; e < En; e += 1024) atomicAdd(&dinv[ed[e]], 1.0f);
    #pragma unroll
    for (int it = 0; it < 8; ++it) {
        int idx = tid + it * 1024;                // float4 index (8192 total)
        float4 v = *(const float4*)(xg + idx * 4);
        halfv4 hv; hv[0]=(_Float16)v.x; hv[1]=(_Float16)v.y;
                   hv[2]=(_Float16)v.z; hv[3]=(_Float16)v.w;
        *(halfv4*)((char*)xs_h + idx * 8) = hv;   // natural [n][f] layout
    }
    {
        int o = tid >> 4, f0 = (tid & 15) * 4;    // 4096 elems / 1024 thr
        float4 v = *(const float4*)(w + o * Fn + f0);
        halfv4 hv; hv[0]=(_Float16)v.x; hv[1]=(_Float16)v.y;
                   hv[2]=(_Float16)v.z; hv[3]=(_Float16)v.w;
        int blk = f0 >> 3, hf = (f0 >> 2) & 1;    // 16B-block XOR swizzle by row
        *(halfv4*)((char*)wts + o * 128 + ((blk ^ (o & 7)) * 16) + hf * 8) = hv;
    }
    __syncthreads();

    // ---- per-node slot count (incl self) + dinv; exclusive prefix scan ----
    int c = 0;
    if (tid < Nn) { float d = dinv[tid]; c = (int)d; dinv[tid] = rsqrtf(d); }
    int v_ = c;
    #pragma unroll
    for (int off = 1; off < 64; off <<= 1) {
        int u = __shfl_up(v_, off, 64);
        if (lane >= off) v_ += u;
    }
    if (wid < 8 && lane == 63) wsum[wid] = v_;
    __syncthreads();
    if (tid == 0) { int a = 0; for (int i = 0; i < 8; ++i) { int t = wsum[i]; wsum[i] = a; a += t; } }
    __syncthreads();
    if (tid < Nn) cnt[tid] = v_ - c + wsum[wid];
    __syncthreads();

    // ---- CSR fill (edges + self-loops) with packed src|norm ----
    for (int e = tid; e < ET; e += 1024) {
        int s, t;
        if (e < En) { s = es[e]; t = ed[e]; } else { s = e - En; t = s; }
        float nrm = dinv[s] * dinv[t];
        int slot = atomicAdd(&cnt[t], 1);         // cnt becomes inclusive prefix
        unsigned short nb = __builtin_bit_cast(unsigned short, (_Float16)nrm);
        epk[slot] = ((unsigned)s << 16) | nb;
    }
    __syncthreads();

    // ---- gather: quarter-wave per target, all-LDS, 4-wide pipelined ----
    {
        const int qid = lane >> 4, fl = lane & 15;  // lane owns features fl*4..+3
        for (int r = 0; r < 8; ++r) {
            int t = r * 64 + wid * 4 + qid;
            int beg = (t == 0) ? 0 : cnt[t - 1];
            int end = cnt[t];
            float a0 = 0.f, a1 = 0.f, a2 = 0.f, a3 = 0.f;
            // prefetched quad (epk padded by +8: safe past end)
            unsigned pA0 = epk[beg],     pA1 = epk[beg + 1];
            unsigned pA2 = epk[beg + 2], pA3 = epk[beg + 3];
            int j = beg;
            for (; j + 4 <= end; j += 4) {
                unsigned pB0 = epk[j + 4], pB1 = epk[j + 5];
                unsigned pB2 = epk[j + 6], pB3 = epk[j + 7];
                int s0 = pA0 >> 16, s1 = pA1 >> 16, s2 = pA2 >> 16, s3 = pA3 >> 16;
                float n0 = pk_norm(pA0), n1 = pk_norm(pA1);
                float n2 = pk_norm(pA2), n3 = pk_norm(pA3);
                halfv4 x0 = *(const halfv4*)((const char*)xs_h + s0 * 128 + fl * 8);
                halfv4 x1 = *(const halfv4*)((const char*)xs_h + s1 * 128 + fl * 8);
                halfv4 x2 = *(const halfv4*)((const char*)xs_h + s2 * 128 + fl * 8);
                halfv4 x3 = *(const halfv4*)((const char*)xs_h + s3 * 128 + fl * 8);
                a0 += n0 * (float)x0[0] + n1 * (float)x1[0] + n2 * (float)x2[0] + n3 * (float)x3[0];
                a1 += n0 * (float)x0[1] + n1 * (float)x1[1] + n2 * (float)x2[1] + n3 * (float)x3[1];
                a2 += n0 * (float)x0[2] + n1 * (float)x1[2] + n2 * (float)x2[2] + n3 * (float)x3[2];
                a3 += n0 * (float)x0[3] + n1 * (float)x1[3] + n2 * (float)x2[3] + n3 * (float)x3[3];
                pA0 = pB0; pA1 = pB1; pA2 = pB2; pA3 = pB3;
            }
            for (; j < end; ++j) {                  // tail (<=3), pk already loaded
                int s = pA0 >> 16;
                float nm = pk_norm(pA0);
                halfv4 xv = *(const halfv4*)((const char*)xs_h + s * 128 + fl * 8);
                a0 += nm * (float)xv[0]; a1 += nm * (float)xv[1];
                a2 += nm * (float)xv[2]; a3 += nm * (float)xv[3];
                pA0 = pA1; pA1 = pA2; pA2 = pA3;
            }
            halfv4 hv; hv[0]=(_Float16)a0; hv[1]=(_Float16)a1;
                       hv[2]=(_Float16)a2; hv[3]=(_Float16)a3;
            // swizzled write: 16B block (fl>>1) XOR (t&7), half (fl&1)
            int dw = t * 32 + (((fl >> 1) ^ (t & 7)) * 4) + (fl & 1) * 2;
            *(halfv4*)((char*)xhs + dw * 4) = hv;
        }
    }
    __syncthreads();

    // ---- conv (transposed tiles): D[o_loc][n_loc] = sum_k W[o][k] xh[n][k] ----
    // A-frag = wts row o (m-index = o), B-frag = xhs row n (n-index = n).
    // D: row = q*4+reg -> o_local, col = m -> n_local. Lane's 4 values are
    // o-contiguous -> one b64 store, XOR-swizzled across the 16 8B-slots of
    // each 128B h-row so the 16 m-lanes of a store hit distinct slots.
    {
        const int m = lane & 15, q = lane >> 4;
        #pragma unroll
        for (int j = 0; j < 8; ++j) {
            int idx = wid * 8 + j, tm = idx >> 2, to = idx & 3;
            int n = tm * 16 + m, o = to * 16 + m;
            halfv8 X0 = *(const halfv8*)((const char*)xhs + n * 128 + ((q       ^ (n & 7)) * 16));
            halfv8 X1 = *(const halfv8*)((const char*)xhs + n * 128 + (((4 + q) ^ (n & 7)) * 16));
            halfv8 W0 = *(const halfv8*)((const char*)wts + o * 128 + ((q       ^ (o & 7)) * 16));
            halfv8 W1 = *(const halfv8*)((const char*)wts + o * 128 + (((4 + q) ^ (o & 7)) * 16));
            f32x4 acc = {0.f, 0.f, 0.f, 0.f};
            acc = __builtin_amdgcn_mfma_f32_16x16x32_f16(W0, X0, acc, 0, 0, 0);
            acc = __builtin_amdgcn_mfma_f32_16x16x32_f16(W1, X1, acc, 0, 0, 0);
            float4 bq = *(const float4*)&wbias[to * 16 + q * 4];
            halfv4 hv;
            hv[0] = (_Float16)fmaxf(acc[0] + bq.x, 0.0f);
            hv[1] = (_Float16)fmaxf(acc[1] + bq.y, 0.0f);
            hv[2] = (_Float16)fmaxf(acc[2] + bq.z, 0.0f);
            hv[3] = (_Float16)fmaxf(acc[3] + bq.w, 0.0f);
            int sw = (to * 4 + q) ^ m;            // 8B slot within row n
            *(halfv4*)((char*)xs_h + n * 128 + sw * 8) = hv;
        }
    }
    __syncthreads();

    // ---- coalesced copyout: unswizzle h rows -> global [n][o] f16 ----
    {
        _Float16* hg = hout + (size_t)g * (Nn * Fn);
        #pragma unroll
        for (int it = 0; it < 8; ++it) {
            int i = tid + it * 1024;              // b64 index (8192 total)
            int n = i >> 4, g64 = i & 15;         // o-group g64 = o>>2
            uint2 vv = *(const uint2*)((const char*)xs_h + (n * 16 + (g64 ^ (n & 15))) * 8);
            *(uint2*)((char*)hg + (size_t)i * 8) = vv;
        }
    }
}

// ---------------- K2: logits partials via MFMA, frags from global ----------------
// GEMM [256 x 32768] (h, f16) x [32768 x 16] (lw^T, fp32->f16 in regs). Grid:
// 32 k-chunks x 16 g-tiles; block = 4 waves = 4 k-quarters; in-block reduce.
__global__ __launch_bounds__(256) void gcn_linear(
    const _Float16* __restrict__ h,   // ws: [256][32768] f16
    const float* __restrict__ lw,     // [16][32768] fp32
    float* __restrict__ part)         // ws: [256][32][16] fp32  ([g][cx][c])
{
    __shared__ float red[4][64][4];
    const int cx = blockIdx.x;        // k-chunk (1024)
    const int gy = blockIdx.y;        // graph tile (16)
    const int tid = threadIdx.x, lane = tid & 63, wid = tid >> 6;
    const int ml = lane & 15, q = lane >> 4;

    const size_t kbase = (size_t)cx * 1024 + wid * 256;
    const _Float16* ha = h  + (size_t)(gy * 16 + ml) * (Nn * Fn) + kbase + q * 8;
    const float*    lb = lw + (size_t)ml * (Nn * Fn) + kbase + q * 8;

    f32x4 acc = {0.f, 0.f, 0.f, 0.f};
    #pragma unroll
    for (int ks = 0; ks < 8; ++ks) {
        halfv8 a = *(const halfv8*)(ha + ks * 32);
        float4 b0 = *(const float4*)(lb + ks * 32);
        float4 b1 = *(const float4*)(lb + ks * 32 + 4);
        halfv8 b; b[0]=(_Float16)b0.x; b[1]=(_Float16)b0.y; b[2]=(_Float16)b0.z;
                  b[3]=(_Float16)b0.w; b[4]=(_Float16)b1.x; b[5]=(_Float16)b1.y;
                  b[6]=(_Float16)b1.z; b[7]=(_Float16)b1.w;
        acc = __builtin_amdgcn_mfma_f32_16x16x32_f16(a, b, acc, 0, 0, 0);
    }
    #pragma unroll
    for (int r = 0; r < 4; ++r) red[wid][lane][r] = acc[r];
    __syncthreads();
    {
        int m = tid >> 4, cc = tid & 15;          // D: row=(lane>>4)*4+reg, col=lane&15
        int sl = (m >> 2) * 16 + cc, rg = m & 3;
        float v = red[0][sl][rg] + red[1][sl][rg] + red[2][sl][rg] + red[3][sl][rg];
        part[(((size_t)(gy * 16 + m)) * 32 + cx) * Cn + cc] = v;
    }
}

// ---------------- K3: reduce 32 slices + bias + log_softmax ----------------
__global__ __launch_bounds__(64) void gcn_softmax(
    const float* __restrict__ part,   // [g][32][16]
    const float* __restrict__ lbias,
    float* __restrict__ out)
{
    const int g = blockIdx.x, lane = threadIdx.x;
    if (lane < Cn) {
        float v = lbias[lane];
        #pragma unroll
        for (int s = 0; s < 32; ++s) v += part[((size_t)g * 32 + s) * Cn + lane];
        float m = v;
        #pragma unroll
        for (int off = 8; off > 0; off >>= 1) m = fmaxf(m, __shfl_xor(m, off, 16));
        float ex = expf(v - m);
        float ssum = ex;
        #pragma unroll
        for (int off = 8; off > 0; off >>= 1) ssum += __shfl_xor(ssum, off, 16);
        out[g * Cn + lane] = v - m - logf(ssum);
    }
}

extern "C" void kernel_launch(void* const* d_in, const int* in_sizes, int n_in,
                              void* d_out, int out_size, void* d_ws, size_t ws_size,
                              hipStream_t stream) {
    const float* x  = (const float*)d_in[0];
    const int*   ei = (const int*)d_in[1];
    const float* w  = (const float*)d_in[2];
    const float* wb = (const float*)d_in[3];
    const float* lw = (const float*)d_in[4];
    const float* lb = (const float*)d_in[5];
    float* out = (float*)d_out;

    _Float16* hbuf = (_Float16*)d_ws;                                // 16 MB
    float* part = (float*)((char*)d_ws + (size_t)Gn * Nn * Fn * 2);  // 512 KB

    hipLaunchKernelGGL(gcn_agg_conv, dim3(Gn), dim3(1024), 0, stream,
                       x, ei, w, wb, hbuf);
    hipLaunchKernelGGL(gcn_linear, dim3(32, 16), dim3(256), 0, stream,
                       hbuf, lw, part);
    hipLaunchKernelGGL(gcn_softmax, dim3(Gn), dim3(64), 0, stream,
                       part, lb, out);
}